// Round 15
// baseline (582.417 us; speedup 1.0000x reference)
//
#include <hip/hip_runtime.h>

// ---------------- CSR construction (unchanged) ----------------

__global__ void count_kernel(const int* __restrict__ dst, int* __restrict__ counts, int E) {
    int e = blockIdx.x * 256 + threadIdx.x;
    if (e < E) atomicAdd(&counts[dst[e]], 1);
}

__global__ void scan_local(const int* __restrict__ counts, int* __restrict__ rowptr,
                           int* __restrict__ bsums, float* __restrict__ dinv, int N) {
    __shared__ int sm[256];
    int t = threadIdx.x;
    int gid = blockIdx.x * 256 + t;
    int v = (gid < N) ? counts[gid] : 0;
    if (gid < N) dinv[gid] = rsqrtf((float)v + 1.0f);
    int x = v;
    sm[t] = x; __syncthreads();
    for (int off = 1; off < 256; off <<= 1) {
        int y = (t >= off) ? sm[t - off] : 0;
        __syncthreads();
        x += y; sm[t] = x; __syncthreads();
    }
    if (gid < N) rowptr[gid] = x - v;
    if (t == 255) bsums[blockIdx.x] = x;
}

__global__ void scan_bsums(int* bsums, int nb) {
    __shared__ int sm[512];
    int t = threadIdx.x;
    int v = (t < nb) ? bsums[t] : 0;
    int x = v;
    sm[t] = x; __syncthreads();
    for (int off = 1; off < 512; off <<= 1) {
        int y = (t >= off) ? sm[t - off] : 0;
        __syncthreads();
        x += y; sm[t] = x; __syncthreads();
    }
    if (t < nb) bsums[t] = x - v;
}

__global__ void scan_add(int* __restrict__ rowptr, const int* __restrict__ bsums, int N) {
    int gid = blockIdx.x * 256 + threadIdx.x;
    if (gid < N) rowptr[gid] += bsums[blockIdx.x];
}

__global__ void fill_kernel(const int* __restrict__ src, const int* __restrict__ dst,
                            const int* __restrict__ rowptr, int* __restrict__ fillc,
                            const float* __restrict__ dinv,
                            int2* __restrict__ edges, int E) {
    int e = blockIdx.x * 256 + threadIdx.x;
    if (e < E) {
        int d = dst[e];
        int s = src[e];
        int pos = rowptr[d] + atomicAdd(&fillc[d], 1);
        edges[pos] = make_int2(s, __float_as_int(dinv[s]));
    }
}

// ---------------- xw = X @ W (unchanged) ----------------

__global__ void __launch_bounds__(128)
gemm64_kernel(const float* __restrict__ X, const float* __restrict__ W,
              float* __restrict__ out, int N) {
    __shared__ float Wl[64 * 64];
    __shared__ float hbuf[2][256];
    int tid = threadIdx.x;
    int lane = tid & 63;
    for (int i = tid; i < 4096; i += 128) Wl[i] = W[i];
    __syncthreads();
    int wi = __builtin_amdgcn_readfirstlane(tid >> 6);
    float* hb = &hbuf[wi][0];
    int g0 = blockIdx.x * 2 + wi;
    int ng = gridDim.x * 2;
    int NG = (N + 3) >> 2;
    for (int g = g0; g < NG; g += ng) {
        int v0 = g * 4;
        float x0 = (v0 + 0 < N) ? X[(size_t)(v0 + 0) * 64 + lane] : 0.f;
        float x1 = (v0 + 1 < N) ? X[(size_t)(v0 + 1) * 64 + lane] : 0.f;
        float x2 = (v0 + 2 < N) ? X[(size_t)(v0 + 2) * 64 + lane] : 0.f;
        float x3 = (v0 + 3 < N) ? X[(size_t)(v0 + 3) * 64 + lane] : 0.f;
        *(float4*)&hb[lane * 4] = make_float4(x0, x1, x2, x3);
        float y0 = 0.f, y1 = 0.f, y2 = 0.f, y3 = 0.f;
#pragma unroll 8
        for (int k = 0; k < 64; ++k) {
            float4 hk = *(const float4*)&hb[k * 4];
            float w = Wl[k * 64 + lane];
            y0 = fmaf(hk.x, w, y0);
            y1 = fmaf(hk.y, w, y1);
            y2 = fmaf(hk.z, w, y2);
            y3 = fmaf(hk.w, w, y3);
        }
        if (v0 + 0 < N) out[(size_t)(v0 + 0) * 64 + lane] = y0;
        if (v0 + 1 < N) out[(size_t)(v0 + 1) * 64 + lane] = y1;
        if (v0 + 2 < N) out[(size_t)(v0 + 2) * 64 + lane] = y2;
        if (v0 + 3 < N) out[(size_t)(v0 + 3) * 64 + lane] = y3;
    }
}

// ------- layer1 agg + @W2: FOUR nodes per wave = 4 independent gather chains -------
// R14 validated 2 chains (213->183us); 4 chains doubles loads-in-flight again.
// Per-chain state ~4 VGPRs -> ~48 total, still under the 64-VGPR occupancy cliff.
// Off-chain j iterations are guard-skipped (wave-uniform scalar branch).

__global__ void agg_mm_kernel(const float* __restrict__ XW, const int2* __restrict__ edges,
                              const int* __restrict__ rowptr, const int* __restrict__ counts,
                              const float* __restrict__ dinv, const float* __restrict__ bias,
                              const float* __restrict__ W2, float* __restrict__ Y, int N) {
    __shared__ float Wl[64 * 64];
    int tid = threadIdx.x;
    for (int i = tid; i < 4096; i += 256) Wl[i] = W2[i];
    __syncthreads();
    int lane = tid & 63, wave = tid >> 6;
    float bb = bias[lane];
    int NP = (N + 3) >> 2;
    int p0 = blockIdx.x * 4 + wave;
    int pstr = gridDim.x * 4;
    for (int p = p0; p < NP; p += pstr) {
        int vb = p * 4;
        int start[4], cnt[4];
        float dv[4], acc[4];
        int cntM = 0;
#pragma unroll
        for (int i = 0; i < 4; ++i) {
            int v = vb + i;
            bool ok = v < N;
            start[i] = ok ? __builtin_amdgcn_readfirstlane(rowptr[v]) : 0;
            cnt[i]   = ok ? __builtin_amdgcn_readfirstlane(counts[v]) : 0;
            dv[i]    = ok ? dinv[v] : 0.f;
            acc[i]   = ok ? dv[i] * XW[(size_t)v * 64 + lane] : 0.f;
            cntM = max(cntM, cnt[i]);
        }
        for (int base = 0; base < cntM; base += 64) {
            int nb[4], idx[4]; float ds[4];
            int nbM = 0;
#pragma unroll
            for (int i = 0; i < 4; ++i) {
                nb[i] = min(64, cnt[i] - base);
                idx[i] = 0; ds[i] = 0.f;
                if (lane < nb[i]) {
                    int2 e = edges[start[i] + base + lane];
                    idx[i] = e.x; ds[i] = __int_as_float(e.y);
                }
                nbM = max(nbM, nb[i]);
            }
            for (int j = 0; j < nbM; ++j) {
#pragma unroll
                for (int i = 0; i < 4; ++i) {
                    if (j < nb[i]) {
                        int s = __shfl(idx[i], j);
                        float d = __shfl(ds[i], j);
                        acc[i] = fmaf(d, XW[(size_t)s * 64 + lane], acc[i]);
                    }
                }
            }
        }
        float h[4], y[4];
#pragma unroll
        for (int i = 0; i < 4; ++i) { h[i] = fmaxf(fmaf(dv[i], acc[i], bb), 0.f); y[i] = 0.f; }
#pragma unroll 8
        for (int k = 0; k < 64; ++k) {
            float w = Wl[k * 64 + lane];
#pragma unroll
            for (int i = 0; i < 4; ++i)
                y[i] = fmaf(__shfl(h[i], k), w, y[i]);
        }
#pragma unroll
        for (int i = 0; i < 4; ++i)
            if (vb + i < N) Y[(size_t)(vb + i) * 64 + lane] = y[i];
    }
}

// ------- layer2 agg + MLP head: FOUR nodes per wave -------

__global__ void agg_head_kernel(const float* __restrict__ Yin, const int2* __restrict__ edges,
                                const int* __restrict__ rowptr, const int* __restrict__ counts,
                                const float* __restrict__ dinv, const float* __restrict__ b2,
                                const float* __restrict__ dW1, const float* __restrict__ db1,
                                const float* __restrict__ dW2, const float* __restrict__ db2,
                                float* __restrict__ out, int N) {
    __shared__ float D1[64 * 64];
    __shared__ float W2l[64 * 16];
    int tid = threadIdx.x;
    for (int i = tid; i < 4096; i += 256) D1[i] = dW1[i];
    for (int i = tid; i < 1024; i += 256) W2l[i] = dW2[i];
    __syncthreads();
    int lane = tid & 63, wave = tid >> 6;
    int c = lane & 15, part = lane >> 4;
    float bbl = b2[lane];
    float bb1 = db1[lane];
    float ob  = db2[c];
    int NP = (N + 3) >> 2;
    int p0 = blockIdx.x * 4 + wave;
    int pstr = gridDim.x * 4;
    for (int p = p0; p < NP; p += pstr) {
        int vb = p * 4;
        int start[4], cnt[4];
        float dv[4], acc[4];
        int cntM = 0;
#pragma unroll
        for (int i = 0; i < 4; ++i) {
            int v = vb + i;
            bool ok = v < N;
            start[i] = ok ? __builtin_amdgcn_readfirstlane(rowptr[v]) : 0;
            cnt[i]   = ok ? __builtin_amdgcn_readfirstlane(counts[v]) : 0;
            dv[i]    = ok ? dinv[v] : 0.f;
            acc[i]   = ok ? dv[i] * Yin[(size_t)v * 64 + lane] : 0.f;
            cntM = max(cntM, cnt[i]);
        }
        for (int base = 0; base < cntM; base += 64) {
            int nb[4], idx[4]; float ds[4];
            int nbM = 0;
#pragma unroll
            for (int i = 0; i < 4; ++i) {
                nb[i] = min(64, cnt[i] - base);
                idx[i] = 0; ds[i] = 0.f;
                if (lane < nb[i]) {
                    int2 e = edges[start[i] + base + lane];
                    idx[i] = e.x; ds[i] = __int_as_float(e.y);
                }
                nbM = max(nbM, nb[i]);
            }
            for (int j = 0; j < nbM; ++j) {
#pragma unroll
                for (int i = 0; i < 4; ++i) {
                    if (j < nb[i]) {
                        int s = __shfl(idx[i], j);
                        float d = __shfl(ds[i], j);
                        acc[i] = fmaf(d, Yin[(size_t)s * 64 + lane], acc[i]);
                    }
                }
            }
        }
        float h2[4], a[4], o[4];
#pragma unroll
        for (int i = 0; i < 4; ++i) { h2[i] = fmaxf(fmaf(dv[i], acc[i], bbl), 0.f); a[i] = bb1; }
#pragma unroll 8
        for (int k = 0; k < 64; ++k) {
            float w = D1[k * 64 + lane];
#pragma unroll
            for (int i = 0; i < 4; ++i)
                a[i] = fmaf(__shfl(h2[i], k), w, a[i]);
        }
#pragma unroll
        for (int i = 0; i < 4; ++i) { a[i] = fmaxf(a[i], 0.f); o[i] = 0.f; }
#pragma unroll 8
        for (int kk = 0; kk < 16; ++kk) {
            float w = W2l[(part * 16 + kk) * 16 + c];
#pragma unroll
            for (int i = 0; i < 4; ++i)
                o[i] = fmaf(__shfl(a[i], part * 16 + kk), w, o[i]);
        }
#pragma unroll
        for (int i = 0; i < 4; ++i) {
            o[i] += __shfl_xor(o[i], 16);
            o[i] += __shfl_xor(o[i], 32);
        }
        if (lane < 16) {
#pragma unroll
            for (int i = 0; i < 4; ++i)
                if (vb + i < N) out[(size_t)(vb + i) * 16 + lane] = o[i] + ob;
        }
    }
}

// ---------------- launch ----------------

extern "C" void kernel_launch(void* const* d_in, const int* in_sizes, int n_in,
                              void* d_out, int out_size, void* d_ws, size_t ws_size,
                              hipStream_t stream) {
    const float* x   = (const float*)d_in[0];
    const int*   ei  = (const int*)d_in[1];
    const float* W1  = (const float*)d_in[2];
    const float* b1  = (const float*)d_in[3];
    const float* W2  = (const float*)d_in[4];
    const float* b2  = (const float*)d_in[5];
    const float* dW1 = (const float*)d_in[6];
    const float* db1 = (const float*)d_in[7];
    const float* dW2 = (const float*)d_in[8];
    const float* db2 = (const float*)d_in[9];
    float* out = (float*)d_out;

    int N = in_sizes[0] / 64;
    int E = in_sizes[1] / 2;
    const int* src = ei;
    const int* dst = ei + E;

    size_t off = 0;
    auto alloc = [&](size_t bytes) {
        void* p = (char*)d_ws + off;
        off += (bytes + 511) & ~(size_t)511;
        return p;
    };
    int Npad = (N + 127) & ~127;
    int*   counts = (int*)alloc((size_t)Npad * 8);     // [counts | fillc]
    int*   fillc  = counts + Npad;
    int*   rowptr = (int*)alloc((size_t)N * 4);
    int*   bsums  = (int*)alloc(512 * 4);
    int2*  edges  = (int2*)alloc((size_t)E * 8);
    float* dinv   = (float*)alloc((size_t)N * 4);
    float* xw     = (float*)alloc((size_t)N * 64 * 4);
    float* yw     = (float*)alloc((size_t)N * 64 * 4);

    hipMemsetAsync(counts, 0, (size_t)Npad * 8, stream);

    int nbN = (N + 255) / 256;
    int nbE = (E + 255) / 256;

    count_kernel<<<nbE, 256, 0, stream>>>(dst, counts, E);
    scan_local<<<nbN, 256, 0, stream>>>(counts, rowptr, bsums, dinv, N);
    scan_bsums<<<1, 512, 0, stream>>>(bsums, nbN);
    scan_add<<<nbN, 256, 0, stream>>>(rowptr, bsums, N);
    fill_kernel<<<nbE, 256, 0, stream>>>(src, dst, rowptr, fillc, dinv, edges, E);

    gemm64_kernel<<<4096, 128, 0, stream>>>(x, W1, xw, N);
    agg_mm_kernel<<<2048, 256, 0, stream>>>(xw, edges, rowptr, counts, dinv, b1, W2, yw, N);
    agg_head_kernel<<<2048, 256, 0, stream>>>(yw, edges, rowptr, counts, dinv, b2,
                                              dW1, db1, dW2, db2, out, N);
}